// Round 1
// baseline (57.209 us; speedup 1.0000x reference)
//
#include <hip/hip_runtime.h>
#include <hip/hip_bf16.h>
#include <math.h>

#define B_DIM 64
#define D_DIM 256
#define C_DIM 100000
#define P_DIM 8
#define N_DIM 32

typedef __attribute__((ext_vector_type(8))) short bf16x8;
typedef __attribute__((ext_vector_type(16))) float f32x16;

__device__ __forceinline__ unsigned short bf16_rn(float f) {
    unsigned int u = __float_as_uint(f);
    unsigned int r = (u + 0x7FFFu + ((u >> 16) & 1u)) >> 16;
    return (unsigned short)r;
}

// Truncate-split: x = hi + lo, hi = truncated-bf16(x) (exact), lo rounds with 2^-17 rel err.
__device__ __forceinline__ void split_bf16(float x, unsigned short& hi, unsigned short& lo) {
    unsigned int bx = __float_as_uint(x);
    unsigned int hb = bx & 0xFFFF0000u;
    hi = (unsigned short)(hb >> 16);
    lo = bf16_rn(x - __uint_as_float(hb));
}

__device__ __forceinline__ float softplusf(float x) { return log1pf(expf(x)); }

// ---------------- Kernel A: norms, sim = ni@ni^T (MFMA), hp/hn losses ----------------
__global__ __launch_bounds__(256)
void prep_kernel(const float* __restrict__ X,
                 const int* __restrict__ pos_idx, const int* __restrict__ pos_mask,
                 const int* __restrict__ neg_idx, const int* __restrict__ neg_mask,
                 float* __restrict__ wsS, float* __restrict__ wsH) {
    __shared__ unsigned short fHi[2048 * 8];   // 32 KB: ni hi fragments (frag order)
    __shared__ unsigned short fLo[2048 * 8];   // 32 KB
    __shared__ float sim[64][64];              // 16 KB
    __shared__ float inv[64];
    __shared__ float hp[64];
    __shared__ float contrib[64];
    const int tid = threadIdx.x;
    if (tid < 64) wsS[tid] = 0.0f;             // zero exp-sum accumulators every call
    // row norms: 4 threads per row
    {
        int r = tid >> 2, q = tid & 3;
        const float* row = X + r * D_DIM + q * 64;
        float s = 0.0f;
        #pragma unroll
        for (int i = 0; i < 64; i += 4) {
            float4 v = *(const float4*)(row + i);
            s += v.x * v.x + v.y * v.y + v.z * v.z + v.w * v.w;
        }
        s += __shfl_xor(s, 1);
        s += __shfl_xor(s, 2);
        if (q == 0) inv[r] = 1.0f / fmaxf(sqrtf(s), 1e-12f);
    }
    __syncthreads();
    // normalized-input fragments: lane l holds M[mt*32+(l&31)][ks*16+8*(l>>5)+j]
    for (int t = tid; t < 2048; t += 256) {
        int l = t & 63, ks = (t >> 6) & 15, mt = t >> 10;
        int row = mt * 32 + (l & 31);
        int col0 = ks * 16 + 8 * (l >> 5);
        const float* src = X + row * D_DIM + col0;
        float iv = inv[row];
        #pragma unroll
        for (int j = 0; j < 8; ++j) {
            unsigned short h, lo;
            split_bf16(src[j] * iv, h, lo);
            fHi[t * 8 + j] = h;
            fLo[t * 8 + j] = lo;
        }
    }
    __syncthreads();
    // sim via 4 wave tiles of 32x32 (A-frag and B-frag layouts coincide for ni@ni^T)
    {
        int w = tid >> 6, l = tid & 63;
        int mt = w >> 1, nt = w & 1;
        f32x16 acc;
        #pragma unroll
        for (int i = 0; i < 16; ++i) acc[i] = 0.0f;
        #pragma unroll
        for (int ks = 0; ks < 16; ++ks) {
            const bf16x8 ah = *(const bf16x8*)&fHi[((mt * 16 + ks) * 64 + l) * 8];
            const bf16x8 al = *(const bf16x8*)&fLo[((mt * 16 + ks) * 64 + l) * 8];
            const bf16x8 bh = *(const bf16x8*)&fHi[((nt * 16 + ks) * 64 + l) * 8];
            const bf16x8 bl = *(const bf16x8*)&fLo[((nt * 16 + ks) * 64 + l) * 8];
            acc = __builtin_amdgcn_mfma_f32_32x32x16_bf16(ah, bh, acc, 0, 0, 0);
            acc = __builtin_amdgcn_mfma_f32_32x32x16_bf16(al, bh, acc, 0, 0, 0);
            acc = __builtin_amdgcn_mfma_f32_32x32x16_bf16(ah, bl, acc, 0, 0, 0);
        }
        #pragma unroll
        for (int r = 0; r < 16; ++r) {
            int brow = mt * 32 + (r & 3) + 8 * (r >> 2) + 4 * (l >> 5);
            int bcol = nt * 32 + (l & 31);
            sim[brow][bcol] = acc[r];
        }
    }
    __syncthreads();
    // hardest positive: min over valid positive pairs (>=1 guaranteed)
    {
        int r = tid >> 2, q = tid & 3;
        const float INF = __int_as_float(0x7f800000);
        float m = INF;
        #pragma unroll
        for (int pp = 0; pp < 2; ++pp) {
            int p = q * 2 + pp;
            int j = pos_idx[r * P_DIM + p];
            int msk = pos_mask[r * P_DIM + p];
            float ps = sim[r][j];
            m = fminf(m, msk ? ps : INF);
        }
        m = fminf(m, __shfl_xor(m, 1));
        m = fminf(m, __shfl_xor(m, 2));
        if (q == 0) hp[r] = m;
    }
    __syncthreads();
    // hard negatives
    {
        int r = tid >> 2, q = tid & 3;
        float thr = hp[r] - 0.3f;
        float sum = 0.0f; int cnt = 0;
        #pragma unroll
        for (int nn = 0; nn < 8; ++nn) {
            int n = q * 8 + nn;
            int j = neg_idx[r * N_DIM + n];
            int msk = neg_mask[r * N_DIM + n];
            float ns = sim[r][j];
            if (msk && (ns > thr)) { cnt += 1; sum += softplusf(ns); }
        }
        sum += __shfl_xor(sum, 1); cnt += __shfl_xor(cnt, 1);
        sum += __shfl_xor(sum, 2); cnt += __shfl_xor(cnt, 2);
        if (q == 0) {
            float hn = (cnt > 0) ? (sum / (float)cnt) : 0.0f;
            contrib[r] = softplusf(-hp[r]) + hn;
        }
    }
    __syncthreads();
    if (tid == 0) {
        float s = 0.0f;
        for (int i = 0; i < 64; ++i) s += contrib[i];
        wsH[0] = s * (1.0f / 64.0f);
    }
}

// ---------------- Kernel B: logits = X @ V^T (split-bf16 MFMA) + partial exp-sums ----------------
__global__ __launch_bounds__(512, 4)
void logits_kernel(const float* __restrict__ X, const float* __restrict__ V,
                   float* __restrict__ out, float* __restrict__ wsS) {
    __shared__ unsigned short fHi[2048 * 8];   // 32 KB raw-input hi fragments
    __shared__ unsigned short fLo[2048 * 8];   // 32 KB
    __shared__ float pw[8][64];
    const int tid = threadIdx.x;
    for (int t = tid; t < 2048; t += 512) {
        int l = t & 63, ks = (t >> 6) & 15, mt = t >> 10;
        int row = mt * 32 + (l & 31);
        int col0 = ks * 16 + 8 * (l >> 5);
        const float* src = X + row * D_DIM + col0;
        #pragma unroll
        for (int j = 0; j < 8; ++j) {
            unsigned short h, lo;
            split_bf16(src[j], h, lo);
            fHi[t * 8 + j] = h;
            fLo[t * 8 + j] = lo;
        }
    }
    pw[tid >> 6][tid & 63] = 0.0f;
    __syncthreads();
    const int w = tid >> 6, l = tid & 63;
    const int c0 = (blockIdx.x * 8 + w) * 32;   // 32 c-columns per wave; C % 32 == 0
    if (c0 < C_DIM) {
        const float* vbase = V + (c0 + (l & 31)) * D_DIM + 8 * (l >> 5);
        f32x16 acc0, acc1;
        #pragma unroll
        for (int i = 0; i < 16; ++i) { acc0[i] = 0.0f; acc1[i] = 0.0f; }
        #pragma unroll 4
        for (int ks = 0; ks < 16; ++ks) {
            float4 r0 = *(const float4*)(vbase + ks * 16);
            float4 r1 = *(const float4*)(vbase + ks * 16 + 4);
            float xs[8] = {r0.x, r0.y, r0.z, r0.w, r1.x, r1.y, r1.z, r1.w};
            bf16x8 vh, vl;
            #pragma unroll
            for (int j = 0; j < 8; ++j) {
                unsigned short h, lo;
                split_bf16(xs[j], h, lo);
                vh[j] = (short)h; vl[j] = (short)lo;
            }
            const bf16x8 ah0 = *(const bf16x8*)&fHi[(ks * 64 + l) * 8];
            const bf16x8 al0 = *(const bf16x8*)&fLo[(ks * 64 + l) * 8];
            const bf16x8 ah1 = *(const bf16x8*)&fHi[((16 + ks) * 64 + l) * 8];
            const bf16x8 al1 = *(const bf16x8*)&fLo[((16 + ks) * 64 + l) * 8];
            acc0 = __builtin_amdgcn_mfma_f32_32x32x16_bf16(ah0, vh, acc0, 0, 0, 0);
            acc0 = __builtin_amdgcn_mfma_f32_32x32x16_bf16(al0, vh, acc0, 0, 0, 0);
            acc0 = __builtin_amdgcn_mfma_f32_32x32x16_bf16(ah0, vl, acc0, 0, 0, 0);
            acc1 = __builtin_amdgcn_mfma_f32_32x32x16_bf16(ah1, vh, acc1, 0, 0, 0);
            acc1 = __builtin_amdgcn_mfma_f32_32x32x16_bf16(al1, vh, acc1, 0, 0, 0);
            acc1 = __builtin_amdgcn_mfma_f32_32x32x16_bf16(ah1, vl, acc1, 0, 0, 0);
        }
        const int c = c0 + (l & 31);
        #pragma unroll
        for (int r = 0; r < 16; ++r) {
            int b0 = (r & 3) + 8 * (r >> 2) + 4 * (l >> 5);
            float v0 = acc0[r];
            out[1 + b0 * C_DIM + c] = v0;
            float e0 = expf(v0);
            #pragma unroll
            for (int m = 1; m <= 16; m <<= 1) e0 += __shfl_xor(e0, m);
            if ((l & 31) == 0) pw[w][b0] = e0;
            int b1 = 32 + b0;
            float v1 = acc1[r];
            out[1 + b1 * C_DIM + c] = v1;
            float e1 = expf(v1);
            #pragma unroll
            for (int m = 1; m <= 16; m <<= 1) e1 += __shfl_xor(e1, m);
            if ((l & 31) == 0) pw[w][b1] = e1;
        }
    }
    __syncthreads();
    if (tid < 64) {
        float s = 0.0f;
        #pragma unroll
        for (int ww = 0; ww < 8; ++ww) s += pw[ww][tid];
        atomicAdd(&wsS[tid], s);
    }
}

// ---------------- Kernel C: finalize loss ----------------
__global__ __launch_bounds__(64)
void final_kernel(float* __restrict__ out, const int* __restrict__ targets,
                  const float* __restrict__ wsS, const float* __restrict__ wsH) {
    __shared__ float lb[64];
    int b = threadIdx.x;
    float S = wsS[b];
    float logZ = logf(S);
    int t = targets[b];
    lb[b] = logZ - out[1 + b * C_DIM + t];
    __syncthreads();
    if (b == 0) {
        float s = 0.0f;
        for (int i = 0; i < 64; ++i) s += lb[i];
        out[0] = s * (1.0f / 64.0f) + wsH[0];
    }
}

extern "C" void kernel_launch(void* const* d_in, const int* in_sizes, int n_in,
                              void* d_out, int out_size, void* d_ws, size_t ws_size,
                              hipStream_t stream) {
    (void)in_sizes; (void)n_in; (void)out_size; (void)ws_size;
    const float* X        = (const float*)d_in[0];
    const float* V        = (const float*)d_in[1];
    const int*   targets  = (const int*)d_in[2];
    const int*   pos_idx  = (const int*)d_in[3];
    const int*   pos_mask = (const int*)d_in[4];
    const int*   neg_idx  = (const int*)d_in[5];
    const int*   neg_mask = (const int*)d_in[6];
    float* out = (float*)d_out;
    float* wsS = (float*)d_ws;        // 64 exp-sum accumulators
    float* wsH = wsS + 64;            // h_loss scalar

    hipLaunchKernelGGL(prep_kernel, dim3(1), dim3(256), 0, stream,
                       X, pos_idx, pos_mask, neg_idx, neg_mask, wsS, wsH);
    const int nblk = (3125 + 7) / 8;  // 3125 wave-tiles of 32 columns
    hipLaunchKernelGGL(logits_kernel, dim3(nblk), dim3(512), 0, stream, X, V, out, wsS);
    hipLaunchKernelGGL(final_kernel, dim3(1), dim3(64), 0, stream, out, targets, wsS, wsH);
}